// Round 1
// baseline (228.533 us; speedup 1.0000x reference)
//
#include <hip/hip_runtime.h>
#include <hip/hip_bf16.h>

typedef float f32x4 __attribute__((ext_vector_type(4)));
typedef short s16x8 __attribute__((ext_vector_type(8)));

#define NROWS 8192
#define KDIM  1024
#define BM 128
#define BN 128
#define BK 32

// round-to-nearest-even fp32 -> bf16 bits, also returns the rounded-back fp32 value
__device__ __forceinline__ unsigned short f2bf(float f, float& back) {
    union { float f; unsigned u; } a; a.f = f;
    unsigned r = a.u + 0x7fffu + ((a.u >> 16) & 1u);
    unsigned short b = (unsigned short)(r >> 16);
    union { unsigned u; float f; } c; c.u = ((unsigned)b) << 16;
    back = c.f;
    return b;
}

__device__ __forceinline__ void gl_lds16(const unsigned short* g, unsigned short* l) {
    __builtin_amdgcn_global_load_lds(
        (const __attribute__((address_space(1))) void*)g,
        (__attribute__((address_space(3))) void*)l, 16, 0, 0);
}

// One block per row: cast row to bf16 (ushort bits) and compute sum of squares
// of the *rounded* values (so the GEMM diagonal matches sq to fp32 noise).
__global__ __launch_bounds__(256)
void prep_kernel(const float* __restrict__ in, unsigned short* __restrict__ abf,
                 float* __restrict__ sq) {
    const int row = blockIdx.x;
    const int t = threadIdx.x;
    const float4 v = reinterpret_cast<const float4*>(in + (size_t)row * KDIM)[t];
    float b0, b1, b2, b3;
    ushort4 u;
    u.x = f2bf(v.x, b0);
    u.y = f2bf(v.y, b1);
    u.z = f2bf(v.z, b2);
    u.w = f2bf(v.w, b3);
    reinterpret_cast<ushort4*>(abf + (size_t)row * KDIM)[t] = u;
    float s = b0 * b0 + b1 * b1 + b2 * b2 + b3 * b3;
    #pragma unroll
    for (int off = 32; off > 0; off >>= 1) s += __shfl_down(s, off);
    __shared__ float red[4];
    if ((t & 63) == 0) red[t >> 6] = s;
    __syncthreads();
    if (t == 0) sq[row] = red[0] + red[1] + red[2] + red[3];
}

// C = A * A^T (bf16 MFMA, fp32 acc), fused epilogue -sqrt(max(sqi+sqj-2c,0)).
// m97 structure: 128x128 tile, BK=32, 4 waves (2x2 of 64x64), global_load_lds
// width-16 staging into linear LDS, ds_read_b128 fragments, 2 barriers/K-step.
__global__ __launch_bounds__(256)
void gemm_kernel(const unsigned short* __restrict__ A, const float* __restrict__ sq,
                 float* __restrict__ out) {
    __shared__ __attribute__((aligned(16))) unsigned short As[BM * BK];
    __shared__ __attribute__((aligned(16))) unsigned short Bs[BN * BK];

    // XCD-aware bijective swizzle: 4096 blocks, 4096 % 8 == 0
    const int bid = blockIdx.x;
    const int cpx = (NROWS / BM) * (NROWS / BN) >> 3;  // 512
    const int swz = (bid & 7) * cpx + (bid >> 3);
    const int brow = (swz >> 6) * BM;   // 64 tiles per row of tiles
    const int bcol = (swz & 63) * BN;

    const int t = threadIdx.x;
    const int lane = t & 63;
    const int wid = t >> 6;
    const int wr = wid >> 1;   // 0..1
    const int wc = wid & 1;    // 0..1

    f32x4 acc[4][4] = {};

    // staging: 8192 B per tile, 256 threads x 16 B x 2 issues
    const int o1 = t * 16;
    const int o2 = o1 + 4096;
    const int r1 = o1 >> 6, c1 = (o1 >> 4) & 3;  // row, 16B-chunk within 64B row
    const int r2 = o2 >> 6, c2 = (o2 >> 4) & 3;

    const unsigned short* Ag1 = A + (size_t)(brow + r1) * KDIM + c1 * 8;
    const unsigned short* Ag2 = A + (size_t)(brow + r2) * KDIM + c2 * 8;
    const unsigned short* Bg1 = A + (size_t)(bcol + r1) * KDIM + c1 * 8;
    const unsigned short* Bg2 = A + (size_t)(bcol + r2) * KDIM + c2 * 8;
    unsigned short* As1 = (unsigned short*)((char*)As + o1);
    unsigned short* As2 = (unsigned short*)((char*)As + o2);
    unsigned short* Bs1 = (unsigned short*)((char*)Bs + o1);
    unsigned short* Bs2 = (unsigned short*)((char*)Bs + o2);

    const int kq = lane >> 4;            // 0..3 -> k-subblock of 8
    const int fr = lane & 15;            // fragment row/col
    const int arow = wr * 64 + fr;
    const int brw  = wc * 64 + fr;

    for (int kk = 0; kk < KDIM; kk += BK) {
        gl_lds16(Ag1 + kk, As1);
        gl_lds16(Ag2 + kk, As2);
        gl_lds16(Bg1 + kk, Bs1);
        gl_lds16(Bg2 + kk, Bs2);
        __syncthreads();   // drains vmcnt before barrier (compiler-inserted)

        s16x8 af[4], bf[4];
        #pragma unroll
        for (int m = 0; m < 4; ++m)
            af[m] = *reinterpret_cast<const s16x8*>(&As[(arow + m * 16) * BK + kq * 8]);
        #pragma unroll
        for (int n = 0; n < 4; ++n)
            bf[n] = *reinterpret_cast<const s16x8*>(&Bs[(brw + n * 16) * BK + kq * 8]);

        #pragma unroll
        for (int m = 0; m < 4; ++m)
            #pragma unroll
            for (int n = 0; n < 4; ++n)
                acc[m][n] = __builtin_amdgcn_mfma_f32_16x16x32_bf16(af[m], bf[n], acc[m][n], 0, 0, 0);
        __syncthreads();   // LDS reuse next iteration
    }

    // Epilogue: C/D layout col = lane&15, row = (lane>>4)*4 + reg  [m89/m91]
    const int ib = brow + wr * 64 + (lane >> 4) * 4;
    const int jb = bcol + wc * 64 + fr;
    float sqj[4];
    #pragma unroll
    for (int n = 0; n < 4; ++n) sqj[n] = sq[jb + n * 16];
    #pragma unroll
    for (int m = 0; m < 4; ++m) {
        #pragma unroll
        for (int r = 0; r < 4; ++r) {
            const int i = ib + m * 16 + r;
            const float sqi = sq[i];
            #pragma unroll
            for (int n = 0; n < 4; ++n) {
                const int j = jb + n * 16;
                const float d2 = sqi + sqj[n] - 2.0f * acc[m][n][r];
                out[(size_t)i * NROWS + j] = -sqrtf(fmaxf(d2, 0.0f));
            }
        }
    }
}

extern "C" void kernel_launch(void* const* d_in, const int* in_sizes, int n_in,
                              void* d_out, int out_size, void* d_ws, size_t ws_size,
                              hipStream_t stream) {
    const float* feat = (const float*)d_in[0];
    float* out = (float*)d_out;
    unsigned short* abf = (unsigned short*)d_ws;                       // 16 MB bf16 copy
    float* sq = (float*)((char*)d_ws + (size_t)NROWS * KDIM * 2);      // 32 KB row sums

    prep_kernel<<<NROWS, 256, 0, stream>>>(feat, abf, sq);

    const int nblocks = (NROWS / BM) * (NROWS / BN);  // 4096
    gemm_kernel<<<nblocks, 256, 0, stream>>>(abf, sq, out);
}

// Round 2
// 141.681 us; speedup vs baseline: 1.6130x; 1.6130x over previous
//
#include <hip/hip_runtime.h>
#include <hip/hip_bf16.h>

typedef float f32x4 __attribute__((ext_vector_type(4)));
typedef short s16x8 __attribute__((ext_vector_type(8)));

#define NROWS 8192
#define KDIM  1024
#define BM 128
#define BN 128
#define BK 32
#define NTILE (NROWS / BM)            // 64 tile-rows
#define NBLK  (NTILE * (NTILE + 1) / 2)  // 2080 upper-tri blocks

// round-to-nearest-even fp32 -> bf16 bits, also returns the rounded-back fp32 value
__device__ __forceinline__ unsigned short f2bf(float f, float& back) {
    union { float f; unsigned u; } a; a.f = f;
    unsigned r = a.u + 0x7fffu + ((a.u >> 16) & 1u);
    unsigned short b = (unsigned short)(r >> 16);
    union { unsigned u; float f; } c; c.u = ((unsigned)b) << 16;
    back = c.f;
    return b;
}

__device__ __forceinline__ void gl_lds16(const unsigned short* g, unsigned short* l) {
    __builtin_amdgcn_global_load_lds(
        (const __attribute__((address_space(1))) void*)g,
        (__attribute__((address_space(3))) void*)l, 16, 0, 0);
}

// One block per row: cast row to bf16 (ushort bits) and compute sum of squares
// of the *rounded* values (so the GEMM diagonal matches sq to fp32 noise).
__global__ __launch_bounds__(256)
void prep_kernel(const float* __restrict__ in, unsigned short* __restrict__ abf,
                 float* __restrict__ sq) {
    const int row = blockIdx.x;
    const int t = threadIdx.x;
    const float4 v = reinterpret_cast<const float4*>(in + (size_t)row * KDIM)[t];
    float b0, b1, b2, b3;
    ushort4 u;
    u.x = f2bf(v.x, b0);
    u.y = f2bf(v.y, b1);
    u.z = f2bf(v.z, b2);
    u.w = f2bf(v.w, b3);
    reinterpret_cast<ushort4*>(abf + (size_t)row * KDIM)[t] = u;
    float s = b0 * b0 + b1 * b1 + b2 * b2 + b3 * b3;
    #pragma unroll
    for (int off = 32; off > 0; off >>= 1) s += __shfl_down(s, off);
    __shared__ float red[4];
    if ((t & 63) == 0) red[t >> 6] = s;
    __syncthreads();
    if (t == 0) sq[row] = red[0] + red[1] + red[2] + red[3];
}

// C = A * A^T upper-triangular tiles only (output is symmetric).
// bf16 MFMA, fp32 acc, fused epilogue -sqrt(max(sqi+sqj-2c,0)).
// Off-diagonal tiles are written twice: direct (scalar, 4x64B rows/instr) and
// mirrored (float4/lane: reg index r is contiguous in the transposed address,
// so the whole fragment stores as one 16B write -> 16x64B rows/instr).
__global__ __launch_bounds__(256)
void gemm_kernel(const unsigned short* __restrict__ A, const float* __restrict__ sq,
                 float* __restrict__ out) {
    __shared__ __attribute__((aligned(16))) unsigned short As[BM * BK];
    __shared__ __attribute__((aligned(16))) unsigned short Bs[BN * BK];

    // XCD-aware swizzle: 2080 blocks, 2080 % 8 == 0 -> bijective
    const int bid = blockIdx.x;
    const int cpx = NBLK >> 3;  // 260
    const int swz = (bid & 7) * cpx + (bid >> 3);

    // triangular decode: swz -> (bi, bj), bi <= bj
    // tiles in rows < r: S(r) = r*(2*NTILE+1-r)/2 = r*(129-r)/2
    int bi = (int)((129.0f - sqrtf(129.0f * 129.0f - 8.0f * (float)swz)) * 0.5f);
    if (bi > NTILE - 1) bi = NTILE - 1;
    if (bi < 0) bi = 0;
    while ((bi + 1) * (129 - (bi + 1)) / 2 <= swz) ++bi;
    while (bi * (129 - bi) / 2 > swz) --bi;
    const int bj = bi + (swz - bi * (129 - bi) / 2);

    const int brow = bi * BM;
    const int bcol = bj * BN;

    const int t = threadIdx.x;
    const int lane = t & 63;
    const int wid = t >> 6;
    const int wr = wid >> 1;   // 0..1
    const int wc = wid & 1;    // 0..1

    f32x4 acc[4][4] = {};

    // staging: 8192 B per tile, 256 threads x 16 B x 2 issues
    const int o1 = t * 16;
    const int o2 = o1 + 4096;
    const int r1 = o1 >> 6, c1 = (o1 >> 4) & 3;  // row, 16B-chunk within 64B row
    const int r2 = o2 >> 6, c2 = (o2 >> 4) & 3;

    const unsigned short* Ag1 = A + (size_t)(brow + r1) * KDIM + c1 * 8;
    const unsigned short* Ag2 = A + (size_t)(brow + r2) * KDIM + c2 * 8;
    const unsigned short* Bg1 = A + (size_t)(bcol + r1) * KDIM + c1 * 8;
    const unsigned short* Bg2 = A + (size_t)(bcol + r2) * KDIM + c2 * 8;
    unsigned short* As1 = (unsigned short*)((char*)As + o1);
    unsigned short* As2 = (unsigned short*)((char*)As + o2);
    unsigned short* Bs1 = (unsigned short*)((char*)Bs + o1);
    unsigned short* Bs2 = (unsigned short*)((char*)Bs + o2);

    const int kq = lane >> 4;            // 0..3 -> k-subblock of 8
    const int fr = lane & 15;            // fragment row/col
    const int arow = wr * 64 + fr;
    const int brw  = wc * 64 + fr;

    for (int kk = 0; kk < KDIM; kk += BK) {
        gl_lds16(Ag1 + kk, As1);
        gl_lds16(Ag2 + kk, As2);
        gl_lds16(Bg1 + kk, Bs1);
        gl_lds16(Bg2 + kk, Bs2);
        __syncthreads();

        s16x8 af[4], bf[4];
        #pragma unroll
        for (int m = 0; m < 4; ++m)
            af[m] = *reinterpret_cast<const s16x8*>(&As[(arow + m * 16) * BK + kq * 8]);
        #pragma unroll
        for (int n = 0; n < 4; ++n)
            bf[n] = *reinterpret_cast<const s16x8*>(&Bs[(brw + n * 16) * BK + kq * 8]);

        #pragma unroll
        for (int m = 0; m < 4; ++m)
            #pragma unroll
            for (int n = 0; n < 4; ++n)
                acc[m][n] = __builtin_amdgcn_mfma_f32_16x16x32_bf16(af[m], bf[n], acc[m][n], 0, 0, 0);
        __syncthreads();
    }

    // Epilogue. C/D layout: col = lane&15 (fr), row = (lane>>4)*4 + reg [m89/m91]
    const int q = lane >> 4;
    const int ib = brow + wr * 64 + q * 4;        // row base for this lane
    const int jb = bcol + wc * 64 + fr;           // col for this lane
    float sqj[4];
    #pragma unroll
    for (int n = 0; n < 4; ++n) sqj[n] = sq[jb + n * 16];

    const bool offdiag = (bi != bj);
    #pragma unroll
    for (int m = 0; m < 4; ++m) {
        #pragma unroll
        for (int n = 0; n < 4; ++n) {
            f32x4 tv;
            #pragma unroll
            for (int r = 0; r < 4; ++r) {
                const int i = ib + m * 16 + r;
                const float d2 = sq[i] + sqj[n] - 2.0f * acc[m][n][r];
                tv[r] = -sqrtf(fmaxf(d2, 0.0f));
            }
            // direct write: out[i, j]
            #pragma unroll
            for (int r = 0; r < 4; ++r) {
                const int i = ib + m * 16 + r;
                out[(size_t)i * NROWS + (jb + n * 16)] = tv[r];
            }
            // mirror write: out[j, i] -- reg index is contiguous -> one float4
            if (offdiag) {
                const size_t mrow = (size_t)(jb + n * 16) * NROWS + (ib + m * 16);
                *reinterpret_cast<float4*>(&out[mrow]) = *(float4*)&tv;
            }
        }
    }
}

extern "C" void kernel_launch(void* const* d_in, const int* in_sizes, int n_in,
                              void* d_out, int out_size, void* d_ws, size_t ws_size,
                              hipStream_t stream) {
    const float* feat = (const float*)d_in[0];
    float* out = (float*)d_out;
    unsigned short* abf = (unsigned short*)d_ws;                       // 16 MB bf16 copy
    float* sq = (float*)((char*)d_ws + (size_t)NROWS * KDIM * 2);      // 32 KB row sums

    prep_kernel<<<NROWS, 256, 0, stream>>>(feat, abf, sq);
    gemm_kernel<<<NBLK, 256, 0, stream>>>(abf, sq, out);
}